// Round 5
// baseline (940.225 us; speedup 1.0000x reference)
//
#include <hip/hip_runtime.h>

#define BN_EPS 1e-5f
#define GATHER_BLOCKS 2048

typedef __attribute__((ext_vector_type(8))) short bf16x8;
typedef __attribute__((ext_vector_type(4))) float f32x4;

__device__ inline float bf2f(unsigned int bits16) {
  return __uint_as_float(bits16 << 16);
}
__device__ inline unsigned short f2bf(float f) {
  unsigned int u = __float_as_uint(f);
  u += 0x7FFFu + ((u >> 16) & 1u);  // RNE
  return (unsigned short)(u >> 16);
}

// ---------------- CSR build ----------------
__global__ void k_count(const int* __restrict__ dst, int* __restrict__ cnt, int E) {
  int e = blockIdx.x * blockDim.x + threadIdx.x;
  if (e < E) atomicAdd(&cnt[dst[e]], 1);
}

// dinv + chunk alloc in one pass
__global__ void k_allocdinv(const int* __restrict__ cnt, float* __restrict__ dinv,
                            int* __restrict__ start, int* __restrict__ cursor,
                            int* __restrict__ total, int n) {
  int i = blockIdx.x * blockDim.x + threadIdx.x;
  if (i < n) {
    int c = cnt[i];
    dinv[i] = rsqrtf((float)c + 1.0f);
    int p = atomicAdd(total, c);
    start[i] = p;
    cursor[i] = p;
  }
}

// elist entry: src (17 bits) | indeg[src] (15 bits)
__global__ void k_place(const int* __restrict__ src, const int* __restrict__ dst,
                        const int* __restrict__ cnt, int* __restrict__ cursor,
                        unsigned int* __restrict__ elist, int E) {
  int e = blockIdx.x * blockDim.x + threadIdx.x;
  if (e >= E) return;
  int s = src[e], d = dst[e];
  int pos = atomicAdd(&cursor[d], 1);
  unsigned int deg = (unsigned int)cnt[s];
  elist[pos] = (unsigned int)s | (deg << 17);
}

// ---------------- input conversions for MFMA ----------------
__global__ void k_xcvt(const float* __restrict__ x, unsigned short* __restrict__ xb, int n) {
  int t = blockIdx.x * blockDim.x + threadIdx.x;
  if (t >= n * 32) return;
  int row = t >> 5, c = t & 31;
  float v = (c < 30) ? x[row * 30 + c] : 0.f;
  xb[t] = f2bf(v);
}

__global__ void k_wcvt(const float* __restrict__ W, unsigned short* __restrict__ Wt,
                       int K, int Kp) {
  int t = blockIdx.x * blockDim.x + threadIdx.x;
  if (t >= 128 * Kp) return;
  int nn = t / Kp, k = t - nn * Kp;
  Wt[t] = f2bf(k < K ? W[k * 128 + nn] : 0.f);
}

// ---------------- MFMA GEMM: C[n,128](bf16) = A[n,Kp](bf16) @ Wt^T ----------------
__global__ void k_gemm_mfma(const unsigned short* __restrict__ A,
                            const unsigned short* __restrict__ Wt,
                            unsigned short* __restrict__ C, int n, int Kp) {
  int wave = threadIdx.x >> 6;
  int lane = threadIdx.x & 63;
  int m0 = blockIdx.x * 128 + wave * 32;
  if (m0 >= n) return;
  int lm = lane & 15;
  int lq = lane >> 4;

  f32x4 acc[2][8] = {};
  const unsigned short* Arow0 = A + (size_t)(m0 + lm) * Kp + lq * 8;
  const unsigned short* Arow1 = Arow0 + (size_t)16 * Kp;
  const unsigned short* Bbase = Wt + (size_t)lm * Kp + lq * 8;

  for (int k0 = 0; k0 < Kp; k0 += 32) {
    bf16x8 a0 = *(const bf16x8*)(Arow0 + k0);
    bf16x8 a1 = *(const bf16x8*)(Arow1 + k0);
#pragma unroll
    for (int t = 0; t < 8; ++t) {
      bf16x8 b = *(const bf16x8*)(Bbase + (size_t)t * 16 * Kp + k0);
      acc[0][t] = __builtin_amdgcn_mfma_f32_16x16x32_bf16(a0, b, acc[0][t], 0, 0, 0);
      acc[1][t] = __builtin_amdgcn_mfma_f32_16x16x32_bf16(a1, b, acc[1][t], 0, 0, 0);
    }
  }
#pragma unroll
  for (int h = 0; h < 2; ++h) {
    int rbase = m0 + h * 16 + lq * 4;
#pragma unroll
    for (int t = 0; t < 8; ++t) {
      int col = t * 16 + lm;
#pragma unroll
      for (int r = 0; r < 4; ++r) {
        int row = rbase + r;
        if (row < n) C[(size_t)row * 128 + col] = f2bf(acc[h][t][r]);
      }
    }
  }
}

// ---------------- CSR gather + fused BN stats ----------------
// grid-stride, block 256 = 4 row-groups x 64 threads; thread = 2 cols (dword bf16x2).
__global__ void k_gather(const unsigned int* __restrict__ elist, const int* __restrict__ start,
                         const int* __restrict__ cnt, const float* __restrict__ dinv,
                         const unsigned int* __restrict__ h,  // bf16x2, row stride 64 dwords
                         const float* __restrict__ bias, float* __restrict__ agg,
                         float* __restrict__ bnsum, int n) {
  int t = threadIdx.x & 63;
  int q = threadIdx.x >> 6;
  float2 bv = ((const float2*)bias)[t];
  float s0 = 0.f, s1 = 0.f, p0 = 0.f, p1 = 0.f;

  for (int row = blockIdx.x * 4 + q; row < n; row += gridDim.x * 4) {
    float di = dinv[row];
    unsigned int hv = h[(size_t)row * 64 + t];
    float acc0 = fmaf(bf2f(hv & 0xFFFFu), di * di, bv.x);
    float acc1 = fmaf(bf2f(hv >> 16),     di * di, bv.y);
    int sbeg = start[row], len = cnt[row];
    const unsigned int* ep = elist + sbeg;
    int j = 0;
    for (; j + 8 <= len; j += 8) {
      unsigned int e0 = ep[j],     e1 = ep[j + 1], e2 = ep[j + 2], e3 = ep[j + 3];
      unsigned int e4 = ep[j + 4], e5 = ep[j + 5], e6 = ep[j + 6], e7 = ep[j + 7];
      unsigned int v0 = h[(size_t)(e0 & 0x1FFFFu) * 64 + t];
      unsigned int v1 = h[(size_t)(e1 & 0x1FFFFu) * 64 + t];
      unsigned int v2 = h[(size_t)(e2 & 0x1FFFFu) * 64 + t];
      unsigned int v3 = h[(size_t)(e3 & 0x1FFFFu) * 64 + t];
      unsigned int v4 = h[(size_t)(e4 & 0x1FFFFu) * 64 + t];
      unsigned int v5 = h[(size_t)(e5 & 0x1FFFFu) * 64 + t];
      unsigned int v6 = h[(size_t)(e6 & 0x1FFFFu) * 64 + t];
      unsigned int v7 = h[(size_t)(e7 & 0x1FFFFu) * 64 + t];
      float w0 = rsqrtf((float)(e0 >> 17) + 1.0f) * di;
      float w1 = rsqrtf((float)(e1 >> 17) + 1.0f) * di;
      float w2 = rsqrtf((float)(e2 >> 17) + 1.0f) * di;
      float w3 = rsqrtf((float)(e3 >> 17) + 1.0f) * di;
      float w4 = rsqrtf((float)(e4 >> 17) + 1.0f) * di;
      float w5 = rsqrtf((float)(e5 >> 17) + 1.0f) * di;
      float w6 = rsqrtf((float)(e6 >> 17) + 1.0f) * di;
      float w7 = rsqrtf((float)(e7 >> 17) + 1.0f) * di;
      acc0 = fmaf(bf2f(v0 & 0xFFFFu), w0, acc0); acc1 = fmaf(bf2f(v0 >> 16), w0, acc1);
      acc0 = fmaf(bf2f(v1 & 0xFFFFu), w1, acc0); acc1 = fmaf(bf2f(v1 >> 16), w1, acc1);
      acc0 = fmaf(bf2f(v2 & 0xFFFFu), w2, acc0); acc1 = fmaf(bf2f(v2 >> 16), w2, acc1);
      acc0 = fmaf(bf2f(v3 & 0xFFFFu), w3, acc0); acc1 = fmaf(bf2f(v3 >> 16), w3, acc1);
      acc0 = fmaf(bf2f(v4 & 0xFFFFu), w4, acc0); acc1 = fmaf(bf2f(v4 >> 16), w4, acc1);
      acc0 = fmaf(bf2f(v5 & 0xFFFFu), w5, acc0); acc1 = fmaf(bf2f(v5 >> 16), w5, acc1);
      acc0 = fmaf(bf2f(v6 & 0xFFFFu), w6, acc0); acc1 = fmaf(bf2f(v6 >> 16), w6, acc1);
      acc0 = fmaf(bf2f(v7 & 0xFFFFu), w7, acc0); acc1 = fmaf(bf2f(v7 >> 16), w7, acc1);
    }
    for (; j < len; ++j) {
      unsigned int e = ep[j];
      unsigned int v = h[(size_t)(e & 0x1FFFFu) * 64 + t];
      float w = rsqrtf((float)(e >> 17) + 1.0f) * di;
      acc0 = fmaf(bf2f(v & 0xFFFFu), w, acc0);
      acc1 = fmaf(bf2f(v >> 16),     w, acc1);
    }
    float2 r; r.x = acc0; r.y = acc1;
    ((float2*)agg)[(size_t)row * 64 + t] = r;
    s0 += acc0; s1 += acc1;
    p0 = fmaf(acc0, acc0, p0); p1 = fmaf(acc1, acc1, p1);
  }

  // block-level column reduction -> bnsum atomics
  __shared__ float4 red[256];
  float4 mine; mine.x = s0; mine.y = s1; mine.z = p0; mine.w = p1;
  red[threadIdx.x] = mine;
  __syncthreads();
  if (threadIdx.x < 64) {
    float4 a = red[threadIdx.x], b = red[threadIdx.x + 64];
    float4 c = red[threadIdx.x + 128], d = red[threadIdx.x + 192];
    atomicAdd(&bnsum[2 * threadIdx.x],           a.x + b.x + c.x + d.x);
    atomicAdd(&bnsum[2 * threadIdx.x + 1],       a.y + b.y + c.y + d.y);
    atomicAdd(&bnsum[128 + 2 * threadIdx.x],     a.z + b.z + c.z + d.z);
    atomicAdd(&bnsum[128 + 2 * threadIdx.x + 1], a.w + b.w + c.w + d.w);
  }
}

__global__ void k_bnfinal(const float* __restrict__ bnsum, const float* __restrict__ gamma,
                          const float* __restrict__ beta, float* __restrict__ scsh, int n) {
  int c = threadIdx.x;  // 128
  float invn = 1.0f / (float)n;
  float mu  = bnsum[c] * invn;
  float ex2 = bnsum[128 + c] * invn;
  float var = fmaxf(ex2 - mu * mu, 0.f);
  float sc = gamma[c] * rsqrtf(var + BN_EPS);
  scsh[c] = sc;
  scsh[128 + c] = fmaf(-mu, sc, beta[c]);
}

// ---------------- BN apply + ReLU -> bf16 (next gemm input) ----------------
__global__ void k_bnapply_bf(const float* __restrict__ a, const float* __restrict__ scsh,
                             unsigned short* __restrict__ xb, int n) {
  int idx = blockIdx.x * blockDim.x + threadIdx.x;  // over n*32 float4s
  if (idx >= n * 32) return;
  int q = idx & 31;
  float4 v  = ((const float4*)a)[idx];
  float4 sc = ((const float4*)scsh)[q];
  float4 sh = ((const float4*)(scsh + 128))[q];
  ushort4 o;
  o.x = f2bf(fmaxf(fmaf(v.x, sc.x, sh.x), 0.f));
  o.y = f2bf(fmaxf(fmaf(v.y, sc.y, sh.y), 0.f));
  o.z = f2bf(fmaxf(fmaf(v.z, sc.z, sh.z), 0.f));
  o.w = f2bf(fmaxf(fmaf(v.w, sc.w, sh.w), 0.f));
  ((ushort4*)xb)[idx] = o;
}

// ---------------- graph boundaries ----------------
__global__ void k_gstart(const int* __restrict__ batch, int* __restrict__ gstart, int n, int G) {
  int g = blockIdx.x * blockDim.x + threadIdx.x;
  if (g > G) return;
  int lo = 0, hi = n;
  while (lo < hi) {
    int mid = (lo + hi) >> 1;
    if (batch[mid] < g) lo = mid + 1; else hi = mid;
  }
  gstart[g] = lo;
}

// ---------------- mean pool over raw agg, fusing final BN+ReLU ----------------
__global__ void k_pool(const float* __restrict__ a, const float* __restrict__ scsh,
                       const int* __restrict__ gstart, float* __restrict__ pooled) {
  int g = blockIdx.x, c = threadIdx.x;  // 128 threads
  int s = gstart[g], e = gstart[g + 1];
  float sc = scsh[c], sh = scsh[128 + c];
  float acc = 0.f;
  for (int i = s; i < e; ++i)
    acc += fmaxf(fmaf(a[(size_t)i * 128 + c], sc, sh), 0.f);
  float cntf = (float)(e - s);
  pooled[(size_t)g * 128 + c] = acc / fmaxf(cntf, 1.f);
}

// ---------------- head MLP ----------------
__global__ void k_head(const float* __restrict__ pooled, const float* __restrict__ HW1,
                       const float* __restrict__ Hb1, const float* __restrict__ HW2,
                       const float* __restrict__ Hb2, float* __restrict__ out) {
  int g = blockIdx.x, j = threadIdx.x;  // 64 threads
  __shared__ float p[128];
  p[j]      = pooled[(size_t)g * 128 + j];
  p[j + 64] = pooled[(size_t)g * 128 + 64 + j];
  __syncthreads();
  float acc = Hb1[j];
  for (int k = 0; k < 128; ++k) acc = fmaf(p[k], HW1[k * 64 + j], acc);
  float v = fmaxf(acc, 0.f) * HW2[j];
  for (int off = 32; off > 0; off >>= 1) v += __shfl_down(v, off);
  if (j == 0) out[g] = v + Hb2[0];
}

extern "C" void kernel_launch(void* const* d_in, const int* in_sizes, int n_in,
                              void* d_out, int out_size, void* d_ws, size_t ws_size,
                              hipStream_t stream) {
  const int F_IN = 30, H = 128;
  const float* x   = (const float*)d_in[0];
  const int* eidx  = (const int*)d_in[1];
  const int* batch = (const int*)d_in[2];
  const int N = in_sizes[0] / F_IN;
  const int E = in_sizes[1] / 2;
  const int G = out_size;
  const int* srcp = eidx;
  const int* dstp = eidx + E;
  const float* HW1 = (const float*)d_in[15];
  const float* Hb1 = (const float*)d_in[16];
  const float* HW2 = (const float*)d_in[17];
  const float* Hb2 = (const float*)d_in[18];
  float* outp = (float*)d_out;

  const int Npad = (N + 127) & ~127;
  size_t nh = (size_t)Npad * H;

  // workspace layout
  unsigned short* bufH = (unsigned short*)d_ws;      // Npad*128 bf16 (gemm out h)
  unsigned short* xbf  = bufH + nh;                  // Npad*128 bf16 (gemm in)
  float* bufX = (float*)(xbf + nh);                  // Npad*128 f32 (agg)
  float* dinv = bufX + nh;                           // N
  int*   cnt    = (int*)(dinv + N);
  int*   startv = cnt + N;
  int*   cursor = startv + N;
  int*   total  = cursor + N;                        // 64 pad
  float* bnsum  = (float*)(total + 64);              // 256
  float* scsh   = bnsum + 256;                       // 256
  float* pooled = scsh + 256;                        // G*128
  int*   gstart = (int*)(pooled + (size_t)G * 128);  // G+1
  unsigned short* Wt0 = (unsigned short*)(gstart + G + 64);  // 128*32
  unsigned short* Wt1 = Wt0 + 128 * 32;                      // 128*128
  unsigned short* Wt2 = Wt1 + 128 * 128;                     // 128*128
  unsigned int* elist = (unsigned int*)(Wt2 + 128 * 128 + 64);  // E entries (4B)

  // ---- build CSR (reused by all 3 layers) ----
  hipMemsetAsync(cnt, 0, (size_t)N * sizeof(int), stream);
  hipMemsetAsync(total, 0, sizeof(int), stream);
  k_count<<<(E + 255) / 256, 256, 0, stream>>>(dstp, cnt, E);
  k_allocdinv<<<(N + 255) / 256, 256, 0, stream>>>(cnt, dinv, startv, cursor, total, N);
  k_place<<<(E + 255) / 256, 256, 0, stream>>>(srcp, dstp, cnt, cursor, elist, E);

  // ---- weights -> transposed bf16; layer-0 x -> bf16 [N,32] ----
  k_wcvt<<<(128 * 32 + 255) / 256, 256, 0, stream>>>((const float*)d_in[3], Wt0, F_IN, 32);
  k_wcvt<<<(128 * 128 + 255) / 256, 256, 0, stream>>>((const float*)d_in[7], Wt1, H, 128);
  k_wcvt<<<(128 * 128 + 255) / 256, 256, 0, stream>>>((const float*)d_in[11], Wt2, H, 128);
  k_xcvt<<<(N * 32 + 255) / 256, 256, 0, stream>>>(x, xbf, N);

  const unsigned short* Wts[3] = {Wt0, Wt1, Wt2};
  for (int l = 0; l < 3; ++l) {
    const float* b  = (const float*)d_in[4 + l * 4];
    const float* gm = (const float*)d_in[5 + l * 4];
    const float* bt = (const float*)d_in[6 + l * 4];
    int Kp = (l == 0) ? 32 : 128;

    k_gemm_mfma<<<Npad / 128, 256, 0, stream>>>(xbf, Wts[l], bufH, N, Kp);
    hipMemsetAsync(bnsum, 0, 256 * sizeof(float), stream);
    k_gather<<<GATHER_BLOCKS, 256, 0, stream>>>(elist, startv, cnt, dinv,
                                                (const unsigned int*)bufH, b, bufX, bnsum, N);
    k_bnfinal<<<1, 128, 0, stream>>>(bnsum, gm, bt, scsh, N);
    if (l < 2)  // last layer's BN+ReLU fused into k_pool
      k_bnapply_bf<<<(N * 32 + 255) / 256, 256, 0, stream>>>(bufX, scsh, xbf, N);
  }

  // pooling (applies layer-2 BN+ReLU) + head
  k_gstart<<<3, 256, 0, stream>>>(batch, gstart, N, G);
  k_pool<<<G, 128, 0, stream>>>(bufX, scsh, gstart, pooled);
  k_head<<<G, 64, 0, stream>>>(pooled, HW1, Hb1, HW2, Hb2, outp);
}